// Round 1
// baseline (803.854 us; speedup 1.0000x reference)
//
#include <hip/hip_runtime.h>

#define EMB_DIM 300
#define ROW_F4  75   // 300 floats = 75 float4 per row; row stride 1200 B is 16B-aligned

__device__ __forceinline__ int lower_bound_i32(const int* __restrict__ a, int n, int key) {
    int lo = 0, hi = n;
    while (lo < hi) {
        int mid = (lo + hi) >> 1;
        if (a[mid] < key) lo = mid + 1; else hi = mid;
    }
    return lo;
}

__global__ __launch_bounds__(256) void emb_seg_mean_kernel(
        const float* __restrict__ emb,      // [VOCAB, 300]
        const int*   __restrict__ word_ids, // [T]
        const int*   __restrict__ seg_ids,  // [T], sorted
        float*       __restrict__ out,      // [S, 300]
        int num_segments, int total_words) {
    const int lane = threadIdx.x & 63;
    const int wave = threadIdx.x >> 6;          // 4 waves per block, 1 segment per wave
    const int s    = blockIdx.x * 4 + wave;
    if (s >= num_segments) return;

    // segment bounds via binary search on sorted segment_ids (wave-uniform)
    const int start = lower_bound_i32(seg_ids, total_words, s);
    const int end   = lower_bound_i32(seg_ids, total_words, s + 1);
    const int count = end - start;

    // coalesced preload of up to 64 word ids; broadcast via shfl in the loop
    int my_id = 0;
    if (start + lane < end) my_id = word_ids[start + lane];

    float4 acc0 = make_float4(0.f, 0.f, 0.f, 0.f);
    float4 acc1 = make_float4(0.f, 0.f, 0.f, 0.f);

    const int nb = count < 64 ? count : 64;
    for (int j = 0; j < nb; ++j) {
        const int id = __shfl(my_id, j);
        const float4* __restrict__ row = (const float4*)(emb + (size_t)id * EMB_DIM);
        float4 r0 = row[lane];                      // chunks 0..63
        acc0.x += r0.x; acc0.y += r0.y; acc0.z += r0.z; acc0.w += r0.w;
        if (lane < ROW_F4 - 64) {                   // chunks 64..74 (lanes 0..10)
            float4 r1 = row[64 + lane];
            acc1.x += r1.x; acc1.y += r1.y; acc1.z += r1.z; acc1.w += r1.w;
        }
    }
    // generic fallback for segments longer than 64 words (not hit in this bench)
    for (int w = start + 64; w < end; ++w) {
        const int id = word_ids[w];
        const float4* __restrict__ row = (const float4*)(emb + (size_t)id * EMB_DIM);
        float4 r0 = row[lane];
        acc0.x += r0.x; acc0.y += r0.y; acc0.z += r0.z; acc0.w += r0.w;
        if (lane < ROW_F4 - 64) {
            float4 r1 = row[64 + lane];
            acc1.x += r1.x; acc1.y += r1.y; acc1.z += r1.z; acc1.w += r1.w;
        }
    }

    const float inv = 1.0f / (float)count;
    float4* __restrict__ orow = (float4*)(out + (size_t)s * EMB_DIM);
    orow[lane] = make_float4(acc0.x * inv, acc0.y * inv, acc0.z * inv, acc0.w * inv);
    if (lane < ROW_F4 - 64)
        orow[64 + lane] = make_float4(acc1.x * inv, acc1.y * inv, acc1.z * inv, acc1.w * inv);
}

extern "C" void kernel_launch(void* const* d_in, const int* in_sizes, int n_in,
                              void* d_out, int out_size, void* d_ws, size_t ws_size,
                              hipStream_t stream) {
    const float* emb      = (const float*)d_in[0];
    const int*   word_ids = (const int*)d_in[1];
    const int*   seg_ids  = (const int*)d_in[2];
    // d_in[3] is num_segments as a device scalar; derive it host-side instead
    float* out = (float*)d_out;

    const int total_words  = in_sizes[1];
    const int num_segments = out_size / EMB_DIM;
    const int blocks = (num_segments + 3) / 4;   // 4 segments (waves) per 256-thread block

    emb_seg_mean_kernel<<<blocks, 256, 0, stream>>>(
        emb, word_ids, seg_ids, out, num_segments, total_words);
}

// Round 2
// 770.122 us; speedup vs baseline: 1.0438x; 1.0438x over previous
//
#include <hip/hip_runtime.h>

#define EMB_DIM 300
#define ROW_F4  75   // 300 floats = 75 float4; row stride 1200 B is 16B-aligned
#define TAIL_F4 (ROW_F4 - 64)   // 11 chunks handled by lanes 0..10

// Phase 1: find segment start offsets (seg_ids sorted, every segment nonempty).
__global__ __launch_bounds__(256) void seg_starts_kernel(
        const int* __restrict__ seg, int T, int S, int* __restrict__ starts) {
    int t = blockIdx.x * 256 + threadIdx.x;
    if (t >= T) return;
    if (t == 0) {
        starts[0] = 0;
        starts[S] = T;          // end sentinel
    } else if (seg[t] != seg[t - 1]) {
        starts[seg[t]] = t;
    }
}

// Phase 2: one wave per segment, 4-way row interleave for MLP.
__global__ __launch_bounds__(256) void emb_seg_mean_kernel(
        const float* __restrict__ emb,       // [VOCAB, 300]
        const int*   __restrict__ word_ids,  // [T]
        const int*   __restrict__ starts,    // [S+1]
        float*       __restrict__ out,       // [S, 300]
        int num_segments) {
    const int lane = threadIdx.x & 63;
    const int s    = blockIdx.x * 4 + (threadIdx.x >> 6);
    if (s >= num_segments) return;

    const int start = starts[s];
    const int end   = starts[s + 1];
    const int count = end - start;

    // coalesced preload of up to 64 word ids; broadcast via shfl
    int my_id = 0;
    if (start + lane < end) my_id = word_ids[start + lane];

    float4 acc  = make_float4(0.f, 0.f, 0.f, 0.f);  // chunk `lane`
    float4 accT = make_float4(0.f, 0.f, 0.f, 0.f);  // chunk 64+lane (lanes 0..10)
    const bool tl = lane < TAIL_F4;

    const int nb = count < 64 ? count : 64;
    int j = 0;
    for (; j + 4 <= nb; j += 4) {
        const int i0 = __shfl(my_id, j);
        const int i1 = __shfl(my_id, j + 1);
        const int i2 = __shfl(my_id, j + 2);
        const int i3 = __shfl(my_id, j + 3);
        const float4* __restrict__ r0 = (const float4*)(emb + (size_t)i0 * EMB_DIM);
        const float4* __restrict__ r1 = (const float4*)(emb + (size_t)i1 * EMB_DIM);
        const float4* __restrict__ r2 = (const float4*)(emb + (size_t)i2 * EMB_DIM);
        const float4* __restrict__ r3 = (const float4*)(emb + (size_t)i3 * EMB_DIM);
        float4 a = r0[lane], b = r1[lane], c = r2[lane], d = r3[lane];
        float4 at, bt, ct, dt;
        if (tl) { at = r0[64 + lane]; bt = r1[64 + lane]; ct = r2[64 + lane]; dt = r3[64 + lane]; }
        acc.x += (a.x + b.x) + (c.x + d.x);
        acc.y += (a.y + b.y) + (c.y + d.y);
        acc.z += (a.z + b.z) + (c.z + d.z);
        acc.w += (a.w + b.w) + (c.w + d.w);
        if (tl) {
            accT.x += (at.x + bt.x) + (ct.x + dt.x);
            accT.y += (at.y + bt.y) + (ct.y + dt.y);
            accT.z += (at.z + bt.z) + (ct.z + dt.z);
            accT.w += (at.w + bt.w) + (ct.w + dt.w);
        }
    }
    for (; j < nb; ++j) {
        const int id = __shfl(my_id, j);
        const float4* __restrict__ r = (const float4*)(emb + (size_t)id * EMB_DIM);
        float4 a = r[lane];
        acc.x += a.x; acc.y += a.y; acc.z += a.z; acc.w += a.w;
        if (tl) {
            float4 at = r[64 + lane];
            accT.x += at.x; accT.y += at.y; accT.z += at.z; accT.w += at.w;
        }
    }
    // generic fallback for segments longer than 64 words (not hit in this bench)
    for (int w = start + 64; w < end; ++w) {
        const int id = word_ids[w];
        const float4* __restrict__ r = (const float4*)(emb + (size_t)id * EMB_DIM);
        float4 a = r[lane];
        acc.x += a.x; acc.y += a.y; acc.z += a.z; acc.w += a.w;
        if (tl) {
            float4 at = r[64 + lane];
            accT.x += at.x; accT.y += at.y; accT.z += at.z; accT.w += at.w;
        }
    }

    const float inv = 1.0f / (float)count;
    float4* __restrict__ orow = (float4*)(out + (size_t)s * EMB_DIM);
    orow[lane] = make_float4(acc.x * inv, acc.y * inv, acc.z * inv, acc.w * inv);
    if (tl)
        orow[64 + lane] = make_float4(accT.x * inv, accT.y * inv, accT.z * inv, accT.w * inv);
}

extern "C" void kernel_launch(void* const* d_in, const int* in_sizes, int n_in,
                              void* d_out, int out_size, void* d_ws, size_t ws_size,
                              hipStream_t stream) {
    const float* emb      = (const float*)d_in[0];
    const int*   word_ids = (const int*)d_in[1];
    const int*   seg_ids  = (const int*)d_in[2];
    float* out = (float*)d_out;
    int* starts = (int*)d_ws;            // S+1 ints of scratch

    const int T = in_sizes[1];
    const int S = out_size / EMB_DIM;

    seg_starts_kernel<<<(T + 255) / 256, 256, 0, stream>>>(seg_ids, T, S, starts);

    const int blocks = (S + 3) / 4;      // 4 segments (waves) per 256-thread block
    emb_seg_mean_kernel<<<blocks, 256, 0, stream>>>(emb, word_ids, starts, out, S);
}